// Round 1
// baseline (1273.282 us; speedup 1.0000x reference)
//
#include <hip/hip_runtime.h>

#define B 32
#define S 2048
#define I 256
#define H 256

typedef _Float16 h2 __attribute__((ext_vector_type(2)));

__device__ __forceinline__ float fdot2(h2 a, h2 b, float c) {
#if __has_builtin(__builtin_amdgcn_fdot2)
    return __builtin_amdgcn_fdot2(a, b, c, false);
#else
    return fmaf((float)a[1], (float)b[1], fmaf((float)a[0], (float)b[0], c));
#endif
}

// lgkm-only workgroup barrier: __syncthreads() drains vmcnt(0) before
// s_barrier; our per-step global ops are thread-private columns so only LDS
// needs cross-wave visibility. imm 0xC07F = vmcnt(63) expcnt(7) lgkmcnt(0).
__device__ __forceinline__ void lds_barrier() {
    __asm__ __volatile__("" ::: "memory");
    __builtin_amdgcn_s_waitcnt(0xC07F);
    __builtin_amdgcn_s_barrier();
    __asm__ __volatile__("" ::: "memory");
}

__device__ __forceinline__ float fast_tanh(float x) {
    float e = __expf(2.0f * x);
    return 1.0f - __fdividef(2.0f, e + 1.0f);
}

// ---------------------------------------------------------------------------
// Phase 1: xw[m][n] = sum_k x[m][k]*Wxw[n][k] + Wxb[n]   (unchanged)
// ---------------------------------------------------------------------------
#define TM 64
#define TN 64
#define TK 32

__global__ __launch_bounds__(256) void phase1_gemm(
    const float* __restrict__ x, const float* __restrict__ Wxw,
    const float* __restrict__ Wxb, float* __restrict__ out)
{
    __shared__ __align__(16) float As[TK][TM + 4];
    __shared__ __align__(16) float Bs[TK][TN + 4];

    const int t  = threadIdx.x;
    const int tn = t & 15, tm = t >> 4;
    const int m0 = blockIdx.x * TM;
    const int n0 = blockIdx.y * TN;

    float acc[4][4] = {};
    float bias[4];
#pragma unroll
    for (int j = 0; j < 4; ++j) bias[j] = Wxb[n0 + 4 * tn + j];

    const int lr = t >> 3;
    const int lc = t & 7;

    for (int kt = 0; kt < I; kt += TK) {
#pragma unroll
        for (int hh = 0; hh < 2; ++hh) {
            const int m = lr + 32 * hh;
            float4 v = *(const float4*)(x   + (size_t)(m0 + m) * I + kt + 4 * lc);
            As[4 * lc + 0][m] = v.x; As[4 * lc + 1][m] = v.y;
            As[4 * lc + 2][m] = v.z; As[4 * lc + 3][m] = v.w;
            float4 w = *(const float4*)(Wxw + (size_t)(n0 + m) * I + kt + 4 * lc);
            Bs[4 * lc + 0][m] = w.x; Bs[4 * lc + 1][m] = w.y;
            Bs[4 * lc + 2][m] = w.z; Bs[4 * lc + 3][m] = w.w;
        }
        __syncthreads();
#pragma unroll
        for (int k = 0; k < TK; ++k) {
            float4 a = *(const float4*)&As[k][4 * tm];
            float4 b = *(const float4*)&Bs[k][4 * tn];
            float av[4] = {a.x, a.y, a.z, a.w};
            float bv[4] = {b.x, b.y, b.z, b.w};
#pragma unroll
            for (int i2 = 0; i2 < 4; ++i2)
#pragma unroll
                for (int j = 0; j < 4; ++j)
                    acc[i2][j] = fmaf(av[i2], bv[j], acc[i2][j]);
        }
        __syncthreads();
    }
#pragma unroll
    for (int i2 = 0; i2 < 4; ++i2) {
        float4 v = { acc[i2][0] + bias[0], acc[i2][1] + bias[1],
                     acc[i2][2] + bias[2], acc[i2][3] + bias[3] };
        *(float4*)(out + (size_t)(m0 + 4 * tm + i2) * H + n0 + 4 * tn) = v;
    }
}

// ---------------------------------------------------------------------------
// Phase 2: h = tanh(xw_s + h @ Whw^T), 2048 steps. 32 blocks x 256 threads.
//
// R4 latency analysis: ~1190 cyc/step vs ~256 cyc VALU floor. The h LDS
// round trip (hsh write -> lgkm -> 8x ds_read_b128 broadcast) is pure
// overhead: wave w consumes exactly the h values its own 64 lanes computed.
// Fix: in-register wave broadcast. After tanh, each lane packs
// (f16(h[2j]), f16(h[2j+1])) via quad_perm DPP + or; the MAC loop pulls each
// k-pair with v_readlane_b32 (wave-uniform -> SGPR) directly into
// v_dot2_f32_f16 (VOP3P allows 1 SGPR operand). Removes hsh entirely:
// no h LDS traffic, no second LDS round trip in the dependency chain.
// pbuf (cross-wave K-partial reduce) stays: 1 f4 write + 1 barrier + 4 b32
// reads per step, double-buffered. Numerics bit-identical to R3 (same f16
// rounding, same pair order, same accumulation order).
// ---------------------------------------------------------------------------
__global__ __launch_bounds__(256, 1) void phase2_rnn(
    const float* __restrict__ Whw, float* __restrict__ out)
{
    __shared__ __align__(16) float pbuf[2][4][H];   // K-partials, dbuf

    const int b = blockIdx.x;
    const int t = threadIdx.x;
    const int w = t >> 6;   // wave id = K-segment
    const int g = t & 63;   // lane -> rows 4g..4g+3

    // wreg[i][j] = W[4g+i][64w + 2j .. 2j+1] as h2. Constant indices only.
    h2 wreg[4][32];
#pragma unroll
    for (int i = 0; i < 4; ++i) {
        const float4* wp = (const float4*)(Whw + (size_t)(4 * g + i) * H + 64 * w);
#pragma unroll
        for (int q = 0; q < 16; ++q) {
            float4 f = wp[q];
            wreg[i][2 * q]     = h2{(_Float16)f.x, (_Float16)f.y};
            wreg[i][2 * q + 1] = h2{(_Float16)f.z, (_Float16)f.w};
        }
    }

    // xw column t of batch b, read/written in place in d_out. 2-deep prefetch;
    // reads up to 2 steps past the end land in the h_last region (in bounds,
    // values unused).
    float* outb = out + (size_t)b * S * H + t;
    float*       op = outb;
    const float* lp = outb + 2 * (size_t)H;
    float xw0 = outb[0], xw1 = outb[(size_t)H];

    float hv = 0.f;
    unsigned packed = 0u;   // even lane 2j holds h2{h[64w+2j], h[64w+2j+1]}
    for (int s = 0; s < S; ++s) {
        const int p = s & 1;
        float xwn = lp[0]; lp += H;          // prefetch xw for step s+2

        // MAC: 4 rows x 64 k (own k-segment); h k-pairs via v_readlane
        // (wave-uniform SGPR operand of fdot2). No LDS on this path.
        float acc0 = 0.f, acc1 = 0.f, acc2 = 0.f, acc3 = 0.f;
#pragma unroll
        for (int j = 0; j < 32; ++j) {
            h2 hh = __builtin_bit_cast(
                h2, __builtin_amdgcn_readlane((int)packed, 2 * j));
            acc0 = fdot2(wreg[0][j], hh, acc0);
            acc1 = fdot2(wreg[1][j], hh, acc1);
            acc2 = fdot2(wreg[2][j], hh, acc2);
            acc3 = fdot2(wreg[3][j], hh, acc3);
        }
        // partials for rows 4g..4g+3: one float4, conflict-free
        float4 part = {acc0, acc1, acc2, acc3};
        *(float4*)&pbuf[p][w][4 * g] = part;

        lds_barrier();

        // thread t reduces row t (stride-1 reads, conflict-free)
        float sum = (pbuf[p][0][t] + pbuf[p][1][t]) +
                    (pbuf[p][2][t] + pbuf[p][3][t]);
        hv = fast_tanh(xw0 + sum);
        op[0] = hv; op += H;                  // outputs[b,s,t]

        // pack next-step h2 in-register: own f16 | neighbor(lane^1) f16 << 16.
        // quad_perm(1,0,3,2) = dpp_ctrl 0xB1. Valid at even lanes (the only
        // lanes readlane touches).
        unsigned f16b = (unsigned)__builtin_bit_cast(
            unsigned short, (_Float16)hv);
        unsigned nb = (unsigned)__builtin_amdgcn_mov_dpp(
            (int)f16b, 0xB1, 0xF, 0xF, false);
        packed = f16b | (nb << 16);

        xw0 = xw1; xw1 = xwn;
    }
    out[(size_t)B * S * H + (size_t)b * H + t] = hv;   // h_last
}

// ---------------------------------------------------------------------------
extern "C" void kernel_launch(void* const* d_in, const int* in_sizes, int n_in,
                              void* d_out, int out_size, void* d_ws, size_t ws_size,
                              hipStream_t stream) {
    const float* x   = (const float*)d_in[0];
    const float* Wxw = (const float*)d_in[1];
    const float* Wxb = (const float*)d_in[2];
    const float* Whw = (const float*)d_in[3];
    float* out = (float*)d_out;

    dim3 g1(B * S / TM, H / TN);   // 1024 x 4
    phase1_gemm<<<g1, 256, 0, stream>>>(x, Wxw, Wxb, out);
    phase2_rnn<<<B, 256, 0, stream>>>(Whw, out);
}